// Round 9
// baseline (155.703 us; speedup 1.0000x reference)
//
#include <hip/hip_runtime.h>
#include <hip/hip_bf16.h>
#include <cstddef>
#include <cstdint>

constexpr int Tt = 8192;
constexpr int Dd = 768;
constexpr int Nn = 10000;
constexpr int Ww = 32;

typedef __bf16 bf16x8 __attribute__((ext_vector_type(8)));
typedef __bf16 bf16x4 __attribute__((ext_vector_type(4)));
typedef _Float16 half8v __attribute__((ext_vector_type(8)));
typedef _Float16 half4v __attribute__((ext_vector_type(4)));
typedef float f32x4 __attribute__((ext_vector_type(4)));

#define MFMA16(a, b, c) __builtin_amdgcn_mfma_f32_16x16x32_bf16((a), (b), (c), 0, 0, 0)
#define MFMAH(a, b, c) __builtin_amdgcn_mfma_f32_16x16x32_f16((a), (b), (c), 0, 0, 0)

// ---------------------------------------------------------------------------
// PREP kernel: one launch does everything span_attn depends on.
//   block 0        : full counting sort of spans (LDS hist, block-local sync)
//   blocks 1..512  : qproj  Qf = fp16(emb) @ fp16(Wq)^T + bq  (fp32 acc)
//                    128x96 tiles, staging converts fp32->fp16 in-register
//                    (identical rounding to the Ef conversion path)
//   blocks 513+    : Ef = fp16(emb)  (6144 blocks, exact)
// Rationale: rounds 2->8 show ~8-10 us serialization per launch; 7 launches
// cost ~55 us of dead time. These three roles are mutually independent.
// ---------------------------------------------------------------------------
__global__ __launch_bounds__(256) void prep_kernel(const float* __restrict__ emb,
                                                   const float* __restrict__ Wq,
                                                   const int* __restrict__ spans,
                                                   const float* __restrict__ bq,
                                                   _Float16* __restrict__ Ef,
                                                   _Float16* __restrict__ Qf,
                                                   int* __restrict__ perm) {
    // LDS union: sort = 8192*4 + 256*4 = 33792 B; qproj = 16K + 12K = 28672 B.
    __shared__ __align__(16) char smem[33792];

    const int b = blockIdx.x;
    const int tid = threadIdx.x;

    if (b == 0) {
        // ---------------- counting sort, entirely in one block ----------------
        int* hist = (int*)smem;            // 8192 bins
        int* part = (int*)(smem + 32768);  // 256 partials
        for (int i = tid; i < 8192; i += 256) hist[i] = 0;
        __syncthreads();
        for (int i = tid; i < Nn; i += 256) atomicAdd(&hist[spans[2 * i]], 1);
        __syncthreads();
        int vals[32];
        int sum = 0;
#pragma unroll
        for (int i = 0; i < 32; ++i) { vals[i] = hist[tid * 32 + i]; sum += vals[i]; }
        part[tid] = sum;
        __syncthreads();
        for (int off = 1; off < 256; off <<= 1) {
            const int v = (tid >= off) ? part[tid - off] : 0;
            __syncthreads();
            part[tid] += v;
            __syncthreads();
        }
        int run = (tid == 0) ? 0 : part[tid - 1];
#pragma unroll
        for (int i = 0; i < 32; ++i) { const int v = vals[i]; hist[tid * 32 + i] = run; run += v; }
        __syncthreads();
        for (int i = tid; i < Nn; i += 256) {
            const int p = atomicAdd(&hist[spans[2 * i]], 1);
            perm[p] = i;
        }
    } else if (b <= 512) {
        // ---------------- qproj (round-8 proven math, fp32 sources) ----------
        _Float16* As = (_Float16*)smem;            // 128 x 64 = 16 KB
        _Float16* Bs = (_Float16*)(smem + 16384);  // 96 x 64  = 12 KB

        const int wave = tid >> 6;
        const int lane = tid & 63;

        // b in 1..512: q = b&7 is the physical XCD (b%8 round-robin); for each
        // q, j = (b-1)>>3 covers 0..63 exactly once -> (mt, nt) bijection with
        // 8 consecutive m-tiles per XCD (A-slice 1.5 MB + Wq 2.4 MB ~ L2).
        const int q  = b & 7;
        const int j  = (b - 1) >> 3;          // 0..63
        const int mt = q * 8 + (j >> 3);      // 0..63
        const int nt = j & 7;                 // 0..7
        const int m0 = mt * 128;
        const int n0 = nt * 96;
        const int wm = (wave & 1) * 64;
        const int wn = (wave >> 1) * 48;
        const int fr = lane & 15;
        const int kg = lane >> 4;

        // Staging: A 1024 segs (4/thread), B 768 segs (3/thread); seg s holds
        // global octet (s&7)^(row&7) -> fragment reads are 2-way (free).
        int ar[4], ao[4];
#pragma unroll
        for (int i = 0; i < 4; ++i) {
            const int s = tid + i * 256;
            ar[i] = s >> 3;
            ao[i] = ((s & 7) ^ (ar[i] & 7)) * 8;
        }
        int br[3], bo[3];
#pragma unroll
        for (int i = 0; i < 3; ++i) {
            const int s = tid + i * 256;
            br[i] = s >> 3;
            bo[i] = ((s & 7) ^ (br[i] & 7)) * 8;
        }

        f32x4 acc[4][3] = {};

        for (int kc = 0; kc < Dd; kc += 64) {
            half8v ra[4], rb[3];
#pragma unroll
            for (int i = 0; i < 4; ++i) {
                const size_t g = (size_t)(m0 + ar[i]) * Dd + kc + ao[i];
                const float4 v0 = *reinterpret_cast<const float4*>(&emb[g]);
                const float4 v1 = *reinterpret_cast<const float4*>(&emb[g + 4]);
                ra[i][0] = (_Float16)v0.x; ra[i][1] = (_Float16)v0.y;
                ra[i][2] = (_Float16)v0.z; ra[i][3] = (_Float16)v0.w;
                ra[i][4] = (_Float16)v1.x; ra[i][5] = (_Float16)v1.y;
                ra[i][6] = (_Float16)v1.z; ra[i][7] = (_Float16)v1.w;
            }
#pragma unroll
            for (int i = 0; i < 3; ++i) {
                const size_t g = (size_t)(n0 + br[i]) * Dd + kc + bo[i];
                const float4 v0 = *reinterpret_cast<const float4*>(&Wq[g]);
                const float4 v1 = *reinterpret_cast<const float4*>(&Wq[g + 4]);
                rb[i][0] = (_Float16)v0.x; rb[i][1] = (_Float16)v0.y;
                rb[i][2] = (_Float16)v0.z; rb[i][3] = (_Float16)v0.w;
                rb[i][4] = (_Float16)v1.x; rb[i][5] = (_Float16)v1.y;
                rb[i][6] = (_Float16)v1.z; rb[i][7] = (_Float16)v1.w;
            }
            __syncthreads();  // previous iteration's LDS reads complete
#pragma unroll
            for (int i = 0; i < 4; ++i)
                *reinterpret_cast<half8v*>(&As[(tid + i * 256) * 8]) = ra[i];
#pragma unroll
            for (int i = 0; i < 3; ++i)
                *reinterpret_cast<half8v*>(&Bs[(tid + i * 256) * 8]) = rb[i];
            __syncthreads();  // writes visible

#pragma unroll
            for (int step = 0; step < 2; ++step) {
                const int g = kg + 4 * step;
                half8v a[4], bb[3];
#pragma unroll
                for (int r = 0; r < 4; ++r) {
                    const int R = wm + r * 16 + fr;
                    a[r] = *reinterpret_cast<const half8v*>(&As[R * 64 + (g ^ (R & 7)) * 8]);
                }
#pragma unroll
                for (int c = 0; c < 3; ++c) {
                    const int R = wn + c * 16 + fr;
                    bb[c] = *reinterpret_cast<const half8v*>(&Bs[R * 64 + (g ^ (R & 7)) * 8]);
                }
#pragma unroll
                for (int r = 0; r < 4; ++r)
#pragma unroll
                    for (int c = 0; c < 3; ++c)
                        acc[r][c] = MFMAH(a[r], bb[c], acc[r][c]);
            }
        }

        // Epilogue: C/D layout col=lane&15, row=(lane>>4)*4+reg.
#pragma unroll
        for (int c = 0; c < 3; ++c) {
            const int ocol = n0 + wn + c * 16 + fr;
            const float bqv = bq[ocol];
#pragma unroll
            for (int r = 0; r < 4; ++r)
#pragma unroll
                for (int jj = 0; jj < 4; ++jj) {
                    const int orow = m0 + wm + r * 16 + kg * 4 + jj;
                    Qf[(size_t)orow * Dd + ocol] = (_Float16)(acc[r][c][jj] + bqv);
                }
        }
    } else {
        // ---------------- Ef conversion (blocks 513..6656, exact) ------------
        const int i = (b - 513) * 256 + tid;  // < Tt*Dd/4 by construction
        const float4 v = reinterpret_cast<const float4*>(emb)[i];
        half4v o;
        o[0] = (_Float16)v.x; o[1] = (_Float16)v.y;
        o[2] = (_Float16)v.z; o[3] = (_Float16)v.w;
        reinterpret_cast<half4v*>(Ef)[i] = o;
    }
}

// ---------------------------------------------------------------------------
// Span attention (round-6/8 verbatim, 53 us proven): fp16, window-shared LDS,
// sync staging, ST=136; softmax + column sums in registers.
// ---------------------------------------------------------------------------
__global__ __launch_bounds__(256) void span_attn_win_kernel(const _Float16* __restrict__ Ef,
                                                            const int* __restrict__ spans,
                                                            const _Float16* __restrict__ Qf,
                                                            const int* __restrict__ perm,
                                                            float* __restrict__ out) {
    constexpr int WR = 48, CH = 128, ST = 136, NCH = Dd / CH;
    __shared__ __align__(16) _Float16 Qs[WR * ST];
    __shared__ __align__(16) _Float16 Es[WR * ST];

    const int tid  = threadIdx.x;
    const int wave = tid >> 6;
    const int lane = tid & 63;

    const int b     = blockIdx.x;
    const int bp    = (b & 7) * 313 + (b >> 3);
    const int slot0 = bp * 4;
    const int slot  = slot0 + wave;
    const bool active = slot < Nn;

    int s0 = perm[slot0 < Nn ? slot0 : (Nn - 1)];
    if ((unsigned)s0 >= (unsigned)Nn) s0 = 0;
    int s = active ? perm[slot] : s0;
    if ((unsigned)s >= (unsigned)Nn) s = 0;

    const int w0    = spans[2 * s0];
    const int start = spans[2 * s];
    const int L     = spans[2 * s + 1] - start + 1;  // 1..32
    const bool big  = L > 16;
    const int sl    = start - w0;
    const bool inwin = active && sl >= 0 && sl <= (WR - 32);

    const int row = lane & 15;  // A-frag m; C-col k
    const int kq  = lane >> 4;

    const size_t gq = (size_t)(start + row) * Dd + kq * 8;  // fallback base

    f32x4 acc00 = {0.f, 0.f, 0.f, 0.f};
    f32x4 acc01 = {0.f, 0.f, 0.f, 0.f};
    f32x4 acc10 = {0.f, 0.f, 0.f, 0.f};
    f32x4 acc11 = {0.f, 0.f, 0.f, 0.f};

    for (int c = 0; c < NCH; ++c) {
        const int c0 = c * CH;
        __syncthreads();  // previous chunk's LDS reads complete
#pragma unroll
        for (int i = 0; i < 3; ++i) {
            const int seg = tid + i * 256;  // 768 segs: 48 rows x 16 col-segs
            const int r  = seg >> 4;
            const int cs = seg & 15;
            const int gr = w0 + r < Tt ? w0 + r : Tt - 1;  // clamp (pad rows unused)
            const size_t ga = (size_t)gr * Dd + c0 + cs * 8;
            *reinterpret_cast<half8v*>(&Qs[r * ST + cs * 8]) =
                *reinterpret_cast<const half8v*>(&Qf[ga]);
            *reinterpret_cast<half8v*>(&Es[r * ST + cs * 8]) =
                *reinterpret_cast<const half8v*>(&Ef[ga]);
        }
        __syncthreads();

        if (inwin) {
            const int ab = (sl + row) * ST + kq * 8;
#pragma unroll
            for (int j = 0; j < 4; ++j) {
                const int o = j * 32;
                const half8v a0 = *reinterpret_cast<const half8v*>(&Qs[ab + o]);
                const half8v b0 = *reinterpret_cast<const half8v*>(&Es[ab + o]);
                acc00 = MFMAH(a0, b0, acc00);
                if (big) {
                    const half8v a1 = *reinterpret_cast<const half8v*>(&Qs[ab + 16 * ST + o]);
                    const half8v b1 = *reinterpret_cast<const half8v*>(&Es[ab + 16 * ST + o]);
                    acc01 = MFMAH(a0, b1, acc01);
                    acc10 = MFMAH(a1, b0, acc10);
                    acc11 = MFMAH(a1, b1, acc11);
                }
            }
        } else if (active) {
            // rare: span exceeds window — direct global fragment loads
#pragma unroll
            for (int j = 0; j < 4; ++j) {
                const int o = c0 + j * 32;
                const half8v a0 = *reinterpret_cast<const half8v*>(&Qf[gq + o]);
                const half8v b0 = *reinterpret_cast<const half8v*>(&Ef[gq + o]);
                acc00 = MFMAH(a0, b0, acc00);
                if (big) {
                    const half8v a1 = *reinterpret_cast<const half8v*>(&Qf[gq + 16 * Dd + o]);
                    const half8v b1 = *reinterpret_cast<const half8v*>(&Ef[gq + 16 * Dd + o]);
                    acc01 = MFMAH(a0, b1, acc01);
                    acc10 = MFMAH(a1, b0, acc10);
                    acc11 = MFMAH(a1, b1, acc11);
                }
            }
        }
    }

    // ---- In-register softmax + column sums ----
    const float NEG = -1e30f;
    const bool kv0 = row < L;
    const bool kv1 = (16 + row) < L;
    float cA, cB;
    {
        float w00[4], w01[4], w10[4], w11[4];
#pragma unroll
        for (int r = 0; r < 4; ++r) {
            float m = kv0 ? acc00[r] : NEG;
            if (big) m = fmaxf(m, kv1 ? acc01[r] : NEG);
#pragma unroll
            for (int st = 1; st <= 8; st <<= 1) m = fmaxf(m, __shfl_xor(m, st));
            const float e0 = kv0 ? __expf(acc00[r] - m) : 0.f;
            const float e1 = (big && kv1) ? __expf(acc01[r] - m) : 0.f;
            float sum = e0 + e1;
#pragma unroll
            for (int st = 1; st <= 8; st <<= 1) sum += __shfl_xor(sum, st);
            const float inv = 1.f / sum;
            const bool qv = (kq * 4 + r) < L;
            w00[r] = qv ? e0 * inv : 0.f;
            w01[r] = qv ? e1 * inv : 0.f;
            if (big) {
                float mh = kv0 ? acc10[r] : NEG;
                mh = fmaxf(mh, kv1 ? acc11[r] : NEG);
#pragma unroll
                for (int st = 1; st <= 8; st <<= 1) mh = fmaxf(mh, __shfl_xor(mh, st));
                const float f0 = kv0 ? __expf(acc10[r] - mh) : 0.f;
                const float f1 = kv1 ? __expf(acc11[r] - mh) : 0.f;
                float sh = f0 + f1;
#pragma unroll
                for (int st = 1; st <= 8; st <<= 1) sh += __shfl_xor(sh, st);
                const float invh = 1.f / sh;
                const bool qvh = (16 + kq * 4 + r) < L;
                w10[r] = qvh ? f0 * invh : 0.f;
                w11[r] = qvh ? f1 * invh : 0.f;
            }
        }
        float pa = w00[0] + w00[1] + w00[2] + w00[3];
        float pb = 0.f;
        if (big) {
            pa += w10[0] + w10[1] + w10[2] + w10[3];
            pb = w01[0] + w01[1] + w01[2] + w01[3] +
                 w11[0] + w11[1] + w11[2] + w11[3];
        }
        pa += __shfl_xor(pa, 16);
        pa += __shfl_xor(pa, 32);
        if (big) {
            pb += __shfl_xor(pb, 16);
            pb += __shfl_xor(pb, 32);
        }
        cA = pa;
        cB = pb;
    }

    // ---- Output: out[s][d] = sum_k c_k * E[start+k][d], fp16 reads ----
    if (active) {
        f32x4 o[3] = {};
        const int KP = (L + 3) & ~3;
        const _Float16* ebase = Ef + (size_t)start * Dd + lane * 4;
        for (int k = 0; k < KP; k += 4) {
            float cv[4];
            half4v ev[4][3];
#pragma unroll
            for (int j = 0; j < 4; ++j) {
                const int kk = k + j;
                cv[j] = (kk < 16) ? __shfl(cA, kk) : __shfl(cB, kk - 16);
#pragma unroll
                for (int i = 0; i < 3; ++i)
                    ev[j][i] = *reinterpret_cast<const half4v*>(ebase + (size_t)kk * Dd + i * 256);
            }
#pragma unroll
            for (int j = 0; j < 4; ++j)
#pragma unroll
                for (int i = 0; i < 3; ++i) {
                    o[i][0] += cv[j] * (float)ev[j][i][0];
                    o[i][1] += cv[j] * (float)ev[j][i][1];
                    o[i][2] += cv[j] * (float)ev[j][i][2];
                    o[i][3] += cv[j] * (float)ev[j][i][3];
                }
        }
#pragma unroll
        for (int i = 0; i < 3; ++i)
            *reinterpret_cast<f32x4*>(&out[(size_t)s * Dd + i * 256 + lane * 4]) = o[i];
    }
}

// ---------------------------------------------------------------------------
// Fallback tier kernels (proven in rounds 2-5) for small ws_size.
// ---------------------------------------------------------------------------
template <bool LO>
__global__ __launch_bounds__(256) void conv_kernel(const float* __restrict__ src,
                                                   __bf16* __restrict__ h,
                                                   __bf16* __restrict__ l, int n4) {
    const int i = blockIdx.x * 256 + threadIdx.x;
    if (i >= n4) return;
    const float4 v = reinterpret_cast<const float4*>(src)[i];
    bf16x4 oh, ol;
    oh[0] = (__bf16)v.x; oh[1] = (__bf16)v.y; oh[2] = (__bf16)v.z; oh[3] = (__bf16)v.w;
    reinterpret_cast<bf16x4*>(h)[i] = oh;
    if (LO) {
        ol[0] = (__bf16)(v.x - (float)oh[0]);
        ol[1] = (__bf16)(v.y - (float)oh[1]);
        ol[2] = (__bf16)(v.z - (float)oh[2]);
        ol[3] = (__bf16)(v.w - (float)oh[3]);
        reinterpret_cast<bf16x4*>(l)[i] = ol;
    }
}

template <bool SPLIT>
__global__ __launch_bounds__(256) void qproj_kernel(const float* __restrict__ emb,
                                                    const float* __restrict__ Wq,
                                                    const float* __restrict__ bq,
                                                    __bf16* __restrict__ Qh,
                                                    __bf16* __restrict__ Ql) {
    __shared__ float As[64][32];
    __shared__ float Bs[64][32];
    const int tid = threadIdx.x;
    const int tx = tid & 15;
    const int ty = tid >> 4;
    const int m0 = blockIdx.x * 64;
    const int n0 = blockIdx.y * 64;

    float acc[4][4] = {};

    for (int kc = 0; kc < Dd; kc += 32) {
#pragma unroll
        for (int i = 0; i < 2; ++i) {
            const int f   = tid + i * 256;
            const int row = f >> 3;
            const int c4  = f & 7;
            const int ph  = (c4 + (row >> 2)) & 7;
            *reinterpret_cast<float4*>(&As[row][ph * 4]) =
                *reinterpret_cast<const float4*>(&emb[(size_t)(m0 + row) * Dd + kc + c4 * 4]);
            *reinterpret_cast<float4*>(&Bs[row][ph * 4]) =
                *reinterpret_cast<const float4*>(&Wq[(size_t)(n0 + row) * Dd + kc + c4 * 4]);
        }
        __syncthreads();
#pragma unroll
        for (int d4 = 0; d4 < 8; ++d4) {
            float4 av[4], bv[4];
#pragma unroll
            for (int r = 0; r < 4; ++r)
                av[r] = *reinterpret_cast<const float4*>(&As[ty * 4 + r][((d4 + ty) & 7) * 4]);
#pragma unroll
            for (int c = 0; c < 4; ++c)
                bv[c] = *reinterpret_cast<const float4*>(&Bs[tx * 4 + c][((d4 + tx) & 7) * 4]);
#pragma unroll
            for (int r = 0; r < 4; ++r)
#pragma unroll
                for (int c = 0; c < 4; ++c) {
                    acc[r][c] += av[r].x * bv[c].x;
                    acc[r][c] += av[r].y * bv[c].y;
                    acc[r][c] += av[r].z * bv[c].z;
                    acc[r][c] += av[r].w * bv[c].w;
                }
        }
        __syncthreads();
    }
#pragma unroll
    for (int r = 0; r < 4; ++r) {
        bf16x4 oh, ol;
#pragma unroll
        for (int c = 0; c < 4; ++c) {
            const float v = acc[r][c] + bq[n0 + tx * 4 + c];
            const __bf16 h = (__bf16)v;
            oh[c] = h;
            if (SPLIT) ol[c] = (__bf16)(v - (float)h);
        }
        const size_t off = (size_t)(m0 + ty * 4 + r) * Dd + n0 + tx * 4;
        *reinterpret_cast<bf16x4*>(&Qh[off]) = oh;
        if (SPLIT) *reinterpret_cast<bf16x4*>(&Ql[off]) = ol;
    }
}

template <bool SPLIT>
__global__ __launch_bounds__(256) void span_attn_g_kernel(const __bf16* __restrict__ Eb,
                                                          const int* __restrict__ spans,
                                                          const __bf16* __restrict__ Qh,
                                                          const __bf16* __restrict__ Ql,
                                                          float* __restrict__ out) {
    const int wave = threadIdx.x >> 6;
    const int lane = threadIdx.x & 63;
    const int s = blockIdx.x * 4 + wave;

    const int start = spans[2 * s];
    const int L     = spans[2 * s + 1] - start + 1;
    const bool big  = L > 16;

    const int row = lane & 15;
    const int kq  = lane >> 4;

    const size_t rbase = (size_t)(start + row) * Dd + kq * 8;
    const __bf16* qh0 = Qh + rbase;
    const __bf16* eb0 = Eb + rbase;
    const __bf16* ql0 = SPLIT ? (Ql + rbase) : nullptr;

    f32x4 acc00 = {0.f, 0.f, 0.f, 0.f};
    f32x4 acc01 = {0.f, 0.f, 0.f, 0.f};
    f32x4 acc10 = {0.f, 0.f, 0.f, 0.f};
    f32x4 acc11 = {0.f, 0.f, 0.f, 0.f};

    for (int kc = 0; kc < Dd; kc += 32) {
        const bf16x8 a0 = *reinterpret_cast<const bf16x8*>(qh0 + kc);
        const bf16x8 b0 = *reinterpret_cast<const bf16x8*>(eb0 + kc);
        acc00 = MFMA16(a0, b0, acc00);
        bf16x8 al0;
        if (SPLIT) {
            al0 = *reinterpret_cast<const bf16x8*>(ql0 + kc);
            acc00 = MFMA16(al0, b0, acc00);
        }
        if (big) {
            const bf16x8 a1 = *reinterpret_cast<const bf16x8*>(qh0 + 16 * Dd + kc);
            const bf16x8 b1 = *reinterpret_cast<const bf16x8*>(eb0 + 16 * Dd + kc);
            acc01 = MFMA16(a0, b1, acc01);
            acc10 = MFMA16(a1, b0, acc10);
            acc11 = MFMA16(a1, b1, acc11);
            if (SPLIT) {
                const bf16x8 al1 = *reinterpret_cast<const bf16x8*>(ql0 + 16 * Dd + kc);
                acc01 = MFMA16(al0, b1, acc01);
                acc10 = MFMA16(al1, b0, acc10);
                acc11 = MFMA16(al1, b1, acc11);
            }
        }
    }

    const float NEG = -1e30f;
    const bool kv0 = row < L;
    const bool kv1 = (16 + row) < L;
    float cA, cB;
    {
        float w00[4], w01[4], w10[4], w11[4];
#pragma unroll
        for (int r = 0; r < 4; ++r) {
            float m = kv0 ? acc00[r] : NEG;
            if (big) m = fmaxf(m, kv1 ? acc01[r] : NEG);
#pragma unroll
            for (int st = 1; st <= 8; st <<= 1) m = fmaxf(m, __shfl_xor(m, st));
            const float e0 = kv0 ? __expf(acc00[r] - m) : 0.f;
            const float e1 = (big && kv1) ? __expf(acc01[r] - m) : 0.f;
            float sum = e0 + e1;
#pragma unroll
            for (int st = 1; st <= 8; st <<= 1) sum += __shfl_xor(sum, st);
            const float inv = 1.f / sum;
            const bool qv = (kq * 4 + r) < L;
            w00[r] = qv ? e0 * inv : 0.f;
            w01[r] = qv ? e1 * inv : 0.f;
            if (big) {
                float mh = kv0 ? acc10[r] : NEG;
                mh = fmaxf(mh, kv1 ? acc11[r] : NEG);
#pragma unroll
                for (int st = 1; st <= 8; st <<= 1) mh = fmaxf(mh, __shfl_xor(mh, st));
                const float f0 = kv0 ? __expf(acc10[r] - mh) : 0.f;
                const float f1 = kv1 ? __expf(acc11[r] - mh) : 0.f;
                float sh = f0 + f1;
#pragma unroll
                for (int st = 1; st <= 8; st <<= 1) sh += __shfl_xor(sh, st);
                const float invh = 1.f / sh;
                const bool qvh = (16 + kq * 4 + r) < L;
                w10[r] = qvh ? f0 * invh : 0.f;
                w11[r] = qvh ? f1 * invh : 0.f;
            }
        }
        float pa = w00[0] + w00[1] + w00[2] + w00[3];
        float pb = 0.f;
        if (big) {
            pa += w10[0] + w10[1] + w10[2] + w10[3];
            pb = w01[0] + w01[1] + w01[2] + w01[3] +
                 w11[0] + w11[1] + w11[2] + w11[3];
        }
        pa += __shfl_xor(pa, 16);
        pa += __shfl_xor(pa, 32);
        if (big) {
            pb += __shfl_xor(pb, 16);
            pb += __shfl_xor(pb, 32);
        }
        cA = pa;
        cB = pb;
    }

    {
        f32x4 o[3] = {};
        const int KP = (L + 3) & ~3;
        const __bf16* ebase = Eb + (size_t)start * Dd + lane * 4;
        for (int k = 0; k < KP; k += 4) {
            float cv[4];
            bf16x4 ev[4][3];
#pragma unroll
            for (int j = 0; j < 4; ++j) {
                const int kk = k + j;
                cv[j] = (kk < 16) ? __shfl(cA, kk) : __shfl(cB, kk - 16);
#pragma unroll
                for (int i = 0; i < 3; ++i)
                    ev[j][i] = *reinterpret_cast<const bf16x4*>(ebase + (size_t)kk * Dd + i * 256);
            }
#pragma unroll
            for (int j = 0; j < 4; ++j)
#pragma unroll
                for (int i = 0; i < 3; ++i) {
                    o[i][0] += cv[j] * (float)ev[j][i][0];
                    o[i][1] += cv[j] * (float)ev[j][i][1];
                    o[i][2] += cv[j] * (float)ev[j][i][2];
                    o[i][3] += cv[j] * (float)ev[j][i][3];
                }
        }
#pragma unroll
        for (int i = 0; i < 3; ++i)
            *reinterpret_cast<f32x4*>(&out[(size_t)s * Dd + i * 256 + lane * 4]) = o[i];
    }
}

// ---------------------------------------------------------------------------
extern "C" void kernel_launch(void* const* d_in, const int* in_sizes, int n_in,
                              void* d_out, int out_size, void* d_ws, size_t ws_size,
                              hipStream_t stream) {
    const float* emb   = (const float*)d_in[0];
    const int*   spans = (const int*)d_in[1];
    const float* Wq    = (const float*)d_in[2];
    const float* bq    = (const float*)d_in[3];
    float*       out   = (float*)d_out;

    const size_t TD = (size_t)Tt * Dd;
    auto align16 = [](size_t x) { return (x + 15) & ~(size_t)15; };

    const size_t needMain = align16(2 * TD * 2) + 10016 * sizeof(int);  // ~25.2 MB
    const size_t needC = 3 * TD * 2;

    if (ws_size >= needMain) {
        char* base = (char*)d_ws;
        _Float16* Qf = (_Float16*)base;
        _Float16* Ef = (_Float16*)(base + TD * 2);
        int* perm = (int*)(base + align16(2 * TD * 2));

        // 1 (sort) + 512 (qproj) + 6144 (Ef conversion) blocks, one launch.
        prep_kernel<<<6657, 256, 0, stream>>>(emb, Wq, spans, bq, Ef, Qf, perm);
        span_attn_win_kernel<<<2504, 256, 0, stream>>>(Ef, spans, Qf, perm, out);
    } else if (ws_size >= needC) {
        // Round-2-style fallback: split bf16, no sort, 3 launches.
        __bf16* w = (__bf16*)d_ws;
        __bf16* Qh = w;
        __bf16* Ql = w + TD;
        __bf16* Eh = w + 2 * TD;
        conv_kernel<false><<<(int)(TD / 4 / 256), 256, 0, stream>>>(emb, Eh, nullptr, (int)(TD / 4));
        qproj_kernel<true><<<dim3(Tt / 64, Dd / 64), 256, 0, stream>>>(emb, Wq, bq, Qh, Ql);
        span_attn_g_kernel<true><<<2500, 256, 0, stream>>>(Eh, spans, Qh, Ql, out);
    } else {
        __bf16* w = (__bf16*)d_ws;
        __bf16* Qh = w;
        __bf16* Eh = w + TD;
        conv_kernel<false><<<(int)(TD / 4 / 256), 256, 0, stream>>>(emb, Eh, nullptr, (int)(TD / 4));
        qproj_kernel<false><<<dim3(Tt / 64, Dd / 64), 256, 0, stream>>>(emb, Wq, bq, Qh, nullptr);
        span_attn_g_kernel<false><<<2500, 256, 0, stream>>>(Eh, spans, Qh, nullptr, out);
    }
}